// Round 3
// baseline (1635.727 us; speedup 1.0000x reference)
//
#include <hip/hip_runtime.h>
#include <cmath>

typedef unsigned long long u64;

#define PRE_TOPN 12000
#define POST_TOPN 2000
#define SORTN 32768
#define TILE 8192
#define NTILE (SORTN / TILE)   // 4 tiles per batch
#define NBLK 188               // 64-bit column blocks covering 12032
#define PADN (NBLK * 64)       // 12032
// triangular bitmap: column-block cb stores rows 0..(cb+1)*64-1
// triOff(cb) = 32*cb*(cb+1); total words per batch:
#define TRI_WORDS (32 * (NBLK - 1) * NBLK + NBLK * 64)  // 1,137,024

__device__ inline u64 shfl_u64(u64 v, int lane) {
    int lo = __shfl((int)(unsigned)(v & 0xffffffffULL), lane);
    int hi = __shfl((int)(unsigned)(v >> 32), lane);
    return ((u64)(unsigned)hi << 32) | (u64)(unsigned)lo;
}

// ---------------------------------------------------------------------------
// Kernel 1: decode boxes (exact fp32 op order, no FMA contraction, exp via
// double) and pack sort keys. key = (~score_bits)<<32 | idx.
// ---------------------------------------------------------------------------
__global__ void decode_pack(const float* __restrict__ anchors,
                            const float* __restrict__ deltas,
                            const float* __restrict__ scores,
                            float* __restrict__ boxes,
                            u64* __restrict__ keys,
                            int N) {
#pragma clang fp contract(off)
    int n = blockIdx.x * blockDim.x + threadIdx.x;
    int b = blockIdx.y;
    if (n >= SORTN) return;
    u64* kb = keys + (size_t)b * SORTN;
    if (n < N) {
        float a0 = anchors[n * 4 + 0];
        float a1 = anchors[n * 4 + 1];
        float a2 = anchors[n * 4 + 2];
        float a3 = anchors[n * 4 + 3];
        float w = (a2 - a0) + 1.0f;
        float h = (a3 - a1) + 1.0f;
        float cx = a0 + 0.5f * w;
        float cy = a1 + 0.5f * h;
        const float* d = deltas + ((size_t)b * N + n) * 4;
        float dx = d[0], dy = d[1], dw = d[2], dh = d[3];
        float px = cx + w * dx;
        float py = cy + h * dy;
        float pw = (float)::exp((double)dw) * w;
        float ph = (float)::exp((double)dh) * h;
        float* bb = boxes + ((size_t)b * N + n) * 4;
        bb[0] = px - 0.5f * pw;
        bb[1] = py - 0.5f * ph;
        bb[2] = px + 0.5f * (pw - 2.0f);
        bb[3] = py + 0.5f * (ph - 2.0f);
        unsigned int sb = __float_as_uint(scores[(size_t)b * N + n]);
        kb[n] = ((u64)(~sb) << 32) | (u64)(unsigned int)n;
    } else {
        kb[n] = ~0ULL;
    }
}

// ---------------------------------------------------------------------------
// Hybrid bitonic sort (unchanged from round 2).
// ---------------------------------------------------------------------------
__global__ __launch_bounds__(1024) void bitonic_local_sort(u64* __restrict__ keys) {
    __shared__ u64 sk[TILE];
    int tile = blockIdx.x;
    u64* kb = keys + (size_t)tile * TILE;
    int base = (tile % NTILE) * TILE;
    for (int i = threadIdx.x; i < TILE; i += 1024) sk[i] = kb[i];
    __syncthreads();
    for (int k = 2; k <= TILE; k <<= 1) {
        for (int j = k >> 1; j > 0; j >>= 1) {
            for (int t = threadIdx.x; t < TILE / 2; t += 1024) {
                int i = ((t & ~(j - 1)) << 1) | (t & (j - 1));
                int ixj = i | j;
                u64 a = sk[i];
                u64 c = sk[ixj];
                bool up = (((base + i) & k) == 0);
                if ((a > c) == up) { sk[i] = c; sk[ixj] = a; }
            }
            __syncthreads();
        }
    }
    for (int i = threadIdx.x; i < TILE; i += 1024) kb[i] = sk[i];
}

__global__ void bitonic_global_step(u64* __restrict__ keys, int k, int j) {
    int t = blockIdx.x * blockDim.x + threadIdx.x;
    int b = t / (SORTN / 2);
    int s = t % (SORTN / 2);
    int i = ((s & ~(j - 1)) << 1) | (s & (j - 1));
    int ixj = i | j;
    u64* kb = keys + (size_t)b * SORTN;
    u64 a = kb[i];
    u64 c = kb[ixj];
    bool up = ((i & k) == 0);
    if ((a > c) == up) { kb[i] = c; kb[ixj] = a; }
}

__global__ __launch_bounds__(1024) void bitonic_local_merge(u64* __restrict__ keys, int k) {
    __shared__ u64 sk[TILE];
    int tile = blockIdx.x;
    u64* kb = keys + (size_t)tile * TILE;
    int base = (tile % NTILE) * TILE;
    bool up = ((base & k) == 0);
    for (int i = threadIdx.x; i < TILE; i += 1024) sk[i] = kb[i];
    __syncthreads();
    for (int j = TILE / 2; j > 0; j >>= 1) {
        for (int t = threadIdx.x; t < TILE / 2; t += 1024) {
            int i = ((t & ~(j - 1)) << 1) | (t & (j - 1));
            int ixj = i | j;
            u64 a = sk[i];
            u64 c = sk[ixj];
            if ((a > c) == up) { sk[i] = c; sk[ixj] = a; }
        }
        __syncthreads();
    }
    for (int i = threadIdx.x; i < TILE; i += 1024) kb[i] = sk[i];
}

// ---------------------------------------------------------------------------
// Gather sorted top-PADN boxes: sbox[b][r] = boxes[b][idx(keys[b][r])].
// Pad rows get a far-away degenerate box (zero IoU with anything real).
// ---------------------------------------------------------------------------
__global__ void gather_sorted(const float* __restrict__ boxes,
                              const u64* __restrict__ keys,
                              float4* __restrict__ sbox, int N) {
    int r = blockIdx.x * 256 + threadIdx.x;
    int b = blockIdx.y;
    if (r >= PADN) return;
    float4 v;
    if (r < PRE_TOPN) {
        u64 key = keys[(size_t)b * SORTN + r];
        int n = (int)(unsigned)(key & 0xffffffffULL);
        v = ((const float4*)boxes)[(size_t)b * N + n];
    } else {
        v = make_float4(-4e8f, -4e8f, -4e8f, -4e8f);
    }
    sbox[(size_t)b * PADN + r] = v;
}

// ---------------------------------------------------------------------------
// Build suppression bitmap. One wave per (row-block rb, 4 column-blocks).
// Lane j holds column box; rows staged in LDS; per row i, all lanes compute
// IoU(row i, col j) and __ballot packs the 64-bit word; lane i keeps it.
// bit set iff j > i AND RN(inter/union) > 0.7f (margin filter; exact div
// only in the ~1e-5 borderline band -> bit-identical decisions).
// Layout: bitmap[b][cb] slab of (cb+1)*64 rows, word index triOff(cb)+row.
// ---------------------------------------------------------------------------
__global__ __launch_bounds__(64) void build_bitmap(const float4* __restrict__ sbox,
                                                   u64* __restrict__ bitmap) {
#pragma clang fp contract(off)
    int rb = blockIdx.x;
    int g  = blockIdx.y;
    int b  = blockIdx.z;
    int cb0 = rb + 4 * g;
    if (cb0 >= NBLK) return;
    int kmax = NBLK - cb0; if (kmax > 4) kmax = 4;
    int lane = threadIdx.x;

    __shared__ float4 rbox[64];
    __shared__ float rarea[64];
    const float4* sb = sbox + (size_t)b * PADN;
    float4 r4 = sb[rb * 64 + lane];
    rbox[lane] = r4;
    rarea[lane] = ((r4.z - r4.x) + 1.0f) * ((r4.w - r4.y) + 1.0f);

    float4 mc[4];
    float aj[4];
    for (int k = 0; k < kmax; ++k) {
        mc[k] = sb[(cb0 + k) * 64 + lane];
        aj[k] = ((mc[k].z - mc[k].x) + 1.0f) * ((mc[k].w - mc[k].y) + 1.0f);
    }
    __syncthreads();

    u64 myword[4] = {0, 0, 0, 0};
    for (int i = 0; i < 64; ++i) {
        float4 bi = rbox[i];
        float ai = rarea[i];
        for (int k = 0; k < 4; ++k) {
            if (k >= kmax) break;
            float xx1 = fmaxf(bi.x, mc[k].x);
            float yy1 = fmaxf(bi.y, mc[k].y);
            float xx2 = fminf(bi.z, mc[k].z);
            float yy2 = fminf(bi.w, mc[k].w);
            float w = fmaxf((xx2 - xx1) + 1.0f, 0.0f);
            float h = fmaxf((yy2 - yy1) + 1.0f, 0.0f);
            float inter = w * h;
            float un = (ai + aj[k]) - inter;
            bool sup = false;
            if (inter > 0.0f) {
                float p = 0.7f * un;
                if (inter > p * (1.0f + 1e-5f)) sup = true;
                else if (inter >= p * (1.0f - 1e-5f)) sup = (inter / un) > 0.7f;
            }
            if (k == 0 && cb0 == rb && lane <= i) sup = false;  // diagonal: j>i only
            u64 m = __ballot(sup);
            if (lane == i) myword[k] = m;
        }
    }
    for (int k = 0; k < kmax; ++k) {
        int cb = cb0 + k;
        size_t idx = (size_t)b * TRI_WORDS + (size_t)32 * cb * (cb + 1) + (size_t)(rb * 64 + lane);
        bitmap[idx] = myword[k];
    }
}

// ---------------------------------------------------------------------------
// Sequential scan: one block per batch. suppressed[188] u64 mask in LDS.
// Per 64-candidate chunk: wave 0 resolves intra-chunk greedy picks from the
// diagonal bitmap word via bit ops + shfl, writes ROIs in pick order; then
// all threads OR the picked rows' bitmap words into suppressed[] (thread t
// owns future word rb+1+t).
// ---------------------------------------------------------------------------
__global__ __launch_bounds__(256) void scan_nms(const float4* __restrict__ sbox,
                                                const u64* __restrict__ bitmap,
                                                float* __restrict__ out) {
    int b = blockIdx.x;
    int tid = threadIdx.x;
    __shared__ u64 suppressed[NBLK];
    __shared__ u64 s_picks;
    __shared__ int s_K;
    if (tid < NBLK) suppressed[tid] = (tid == NBLK - 1) ? 0xFFFFFFFF00000000ULL : 0ULL;  // cols >= 12000 invalid
    if (tid == 0) s_K = 0;
    const u64* bm = bitmap + (size_t)b * TRI_WORDS;

    for (int rb = 0; rb < NBLK; ++rb) {
        __syncthreads();
        int K = s_K;
        if (K >= POST_TOPN) break;
        if (tid < 64) {
            int c = tid;
            int base = rb * 64;
            u64 myrow = bm[(size_t)32 * rb * (rb + 1) + (size_t)(base + c)];
            float4 mybox = sbox[(size_t)b * PADN + base + c];
            u64 alive = ~suppressed[rb];
            u64 picks = 0;
            u64 cur = alive;
            while (cur) {
                int i = __ffsll((long long)cur) - 1;
                picks |= 1ULL << i;
                u64 row = shfl_u64(myrow, i);
                alive &= ~row;
                cur = alive & ~((2ULL << i) - 1ULL);
            }
            int avail = POST_TOPN - K;
            int np = __popcll(picks);
            while (np > avail) {                       // truncate highest (latest) picks
                picks &= ~(1ULL << (63 - __clzll(picks)));
                --np;
            }
            if (c == 0) { s_picks = picks; s_K = K + np; }
            if ((picks >> c) & 1ULL) {
                int rank = __popcll(picks & ((1ULL << c) - 1ULL));
                float* o = out + ((size_t)b * POST_TOPN + K + rank) * 5;
                o[0] = (float)b; o[1] = mybox.x; o[2] = mybox.y; o[3] = mybox.z; o[4] = mybox.w;
            }
        }
        __syncthreads();
        u64 pk = s_picks;
        if (pk) {
            int w = rb + 1 + tid;
            if (w < NBLK) {
                u64 acc = suppressed[w];
                const u64* col = bm + (size_t)32 * w * (w + 1) + (size_t)(rb * 64);
                u64 p2 = pk;
                while (p2) {
                    int i = __ffsll((long long)p2) - 1;
                    acc |= col[i];
                    p2 &= p2 - 1;
                }
                suppressed[w] = acc;
            }
        }
    }
    __syncthreads();
    int K = s_K;
    for (int r = K + tid; r < POST_TOPN; r += 256) {
        float* o = out + ((size_t)b * POST_TOPN + r) * 5;
        o[0] = 0.0f; o[1] = 0.0f; o[2] = 0.0f; o[3] = 0.0f; o[4] = 0.0f;
    }
}

// ---------------------------------------------------------------------------
// Fallback (round-2) NMS kernel — used only if ws_size can't hold the bitmap.
// ---------------------------------------------------------------------------
__global__ __launch_bounds__(1024) void nms_kernel(const float* __restrict__ boxes,
                                                   const u64* __restrict__ keys,
                                                   float* __restrict__ out,
                                                   int N) {
#pragma clang fp contract(off)
    __shared__ float4 kbox[POST_TOPN];
    __shared__ float kar[POST_TOPN];
    __shared__ float4 cbox[64];
    __shared__ float car_s[64];
    __shared__ int supp[64];
    __shared__ int s_cnt;

    int b = blockIdx.x;
    int tid = threadIdx.x;
    const u64* kb = keys + (size_t)b * SORTN;
    const float* bb = boxes + (size_t)b * N * 4;

    if (tid == 0) s_cnt = 0;
    __syncthreads();

    for (int start = 0; start < PRE_TOPN; start += 64) {
        int K = s_cnt;
        if (K >= POST_TOPN) break;
        int csize = min(64, PRE_TOPN - start);

        if (tid < 64) {
            int c = tid;
            if (c < csize) {
                u64 key = kb[start + c];
                int n = (int)(unsigned int)(key & 0xFFFFFFFFULL);
                const float* p = bb + (size_t)n * 4;
                float x1 = p[0], y1 = p[1], x2 = p[2], y2 = p[3];
                cbox[c] = make_float4(x1, y1, x2, y2);
                car_s[c] = ((x2 - x1) + 1.0f) * ((y2 - y1) + 1.0f);
            }
            supp[c] = 0;
        }
        __syncthreads();

        {
            int c = tid & 63;
            int sl = tid >> 6;
            if (c < csize) {
                float4 me = cbox[c];
                float ar = car_s[c];
                int flag = 0;
                for (int kk = sl; kk < K; kk += 16) {
                    float4 k0 = kbox[kk];
                    float a0 = kar[kk];
                    float xx1 = fmaxf(k0.x, me.x);
                    float yy1 = fmaxf(k0.y, me.y);
                    float xx2 = fminf(k0.z, me.z);
                    float yy2 = fminf(k0.w, me.w);
                    float w0 = fmaxf((xx2 - xx1) + 1.0f, 0.0f);
                    float h0 = fmaxf((yy2 - yy1) + 1.0f, 0.0f);
                    float inter0 = w0 * h0;
                    float iou0 = inter0 / ((a0 + ar) - inter0);
                    if (iou0 > 0.7f) { flag = 1; break; }
                }
                if (flag) supp[c] = 1;
            }
        }
        __syncthreads();

        if (tid < 64) {
            int c = tid;
            bool alive = (c < csize) && (supp[c] == 0);
            float4 me = cbox[c];
            float ar = car_s[c];
            int cnt = K;
            u64 m = __ballot(alive);
            while (m != 0 && cnt < POST_TOPN) {
                int i = __ffsll((unsigned long long)m) - 1;
                float ix1 = __shfl(me.x, i);
                float iy1 = __shfl(me.y, i);
                float ix2 = __shfl(me.z, i);
                float iy2 = __shfl(me.w, i);
                float iar = __shfl(ar, i);
                if (c == i) {
                    kbox[cnt] = me;
                    kar[cnt] = ar;
                    float* o = out + ((size_t)b * POST_TOPN + cnt) * 5;
                    o[0] = (float)b; o[1] = me.x; o[2] = me.y; o[3] = me.z; o[4] = me.w;
                }
                if (alive && c > i) {
                    float xx1 = fmaxf(ix1, me.x);
                    float yy1 = fmaxf(iy1, me.y);
                    float xx2 = fminf(ix2, me.z);
                    float yy2 = fminf(iy2, me.w);
                    float w = fmaxf((xx2 - xx1) + 1.0f, 0.0f);
                    float h = fmaxf((yy2 - yy1) + 1.0f, 0.0f);
                    float inter = w * h;
                    float iou = inter / ((iar + ar) - inter);
                    if (iou > 0.7f) alive = false;
                }
                cnt++;
                m = __ballot(alive);
                u64 clearmask = (2ULL << i) - 1ULL;
                m &= ~clearmask;
            }
            if (c == 0) s_cnt = cnt;
        }
        __syncthreads();
    }

    __syncthreads();
    int K = s_cnt;
    for (int r = K + tid; r < POST_TOPN; r += (int)blockDim.x) {
        float* o = out + ((size_t)b * POST_TOPN + r) * 5;
        o[0] = 0.0f; o[1] = 0.0f; o[2] = 0.0f; o[3] = 0.0f; o[4] = 0.0f;
    }
}

// ---------------------------------------------------------------------------
extern "C" void kernel_launch(void* const* d_in, const int* in_sizes, int n_in,
                              void* d_out, int out_size, void* d_ws, size_t ws_size,
                              hipStream_t stream) {
    const float* anchors = (const float*)d_in[0];
    const float* deltas  = (const float*)d_in[1];
    const float* scores  = (const float*)d_in[2];
    float* out = (float*)d_out;

    int N = in_sizes[0] / 4;           // 27380
    int B = in_sizes[2] / N;           // 8

    // workspace layout (256B-aligned sections)
    size_t off = 0;
    auto take = [&](size_t bytes) { size_t o = off; off = (off + bytes + 255) & ~(size_t)255; return o; };
    size_t boxesOff  = take((size_t)B * N * 4 * sizeof(float));
    size_t keysOff   = take((size_t)B * SORTN * sizeof(u64));
    size_t sboxOff   = take((size_t)B * PADN * sizeof(float4));
    size_t bitmapOff = take((size_t)B * TRI_WORDS * sizeof(u64));
    bool bitmap_path = (off <= ws_size);

    float* boxes = (float*)((char*)d_ws + boxesOff);
    u64*   keys  = (u64*)((char*)d_ws + keysOff);

    dim3 g1((unsigned)((SORTN + 255) / 256), (unsigned)B);
    decode_pack<<<g1, 256, 0, stream>>>(anchors, deltas, scores, boxes, keys, N);

    int ntiles = B * NTILE;
    bitonic_local_sort<<<ntiles, 1024, 0, stream>>>(keys);
    int gsteps = B * (SORTN / 2) / 256;
    bitonic_global_step<<<gsteps, 256, 0, stream>>>(keys, 2 * TILE, TILE);
    bitonic_local_merge<<<ntiles, 1024, 0, stream>>>(keys, 2 * TILE);
    bitonic_global_step<<<gsteps, 256, 0, stream>>>(keys, 4 * TILE, 2 * TILE);
    bitonic_global_step<<<gsteps, 256, 0, stream>>>(keys, 4 * TILE, TILE);
    bitonic_local_merge<<<ntiles, 1024, 0, stream>>>(keys, 4 * TILE);

    if (bitmap_path) {
        float4* sbox = (float4*)((char*)d_ws + sboxOff);
        u64* bitmap  = (u64*)((char*)d_ws + bitmapOff);
        dim3 gg((unsigned)((PADN + 255) / 256), (unsigned)B);
        gather_sorted<<<gg, 256, 0, stream>>>(boxes, keys, sbox, N);
        dim3 gb((unsigned)NBLK, (unsigned)((NBLK + 3) / 4), (unsigned)B);
        build_bitmap<<<gb, 64, 0, stream>>>(sbox, bitmap);
        scan_nms<<<B, 256, 0, stream>>>(sbox, bitmap, out);
    } else {
        nms_kernel<<<B, 1024, 0, stream>>>(boxes, keys, out, N);
    }
}

// Round 4
// 1027.495 us; speedup vs baseline: 1.5920x; 1.5920x over previous
//
#include <hip/hip_runtime.h>
#include <cmath>

typedef unsigned long long u64;

#define PRE_TOPN 12000
#define POST_TOPN 2000
#define SORTN 32768
#define TILE 8192
#define NTILE (SORTN / TILE)   // 4 tiles per batch
#define NBLK 188               // 64-bit column blocks covering 12032
#define PADN (NBLK * 64)       // 12032
// triangular bitmap: column-block cb stores rows 0..(cb+1)*64-1
// triOff(cb) = 32*cb*(cb+1); total words per batch:
#define TRI_WORDS (32 * (NBLK - 1) * NBLK + NBLK * 64)  // 1,137,024

__device__ inline u64 shfl_u64(u64 v, int lane) {
    int lo = __shfl((int)(unsigned)(v & 0xffffffffULL), lane);
    int hi = __shfl((int)(unsigned)(v >> 32), lane);
    return ((u64)(unsigned)hi << 32) | (u64)(unsigned)lo;
}

// ---------------------------------------------------------------------------
// Kernel 1: decode boxes (exact fp32 op order, no FMA contraction, exp via
// double) and pack sort keys. key = (~score_bits)<<32 | idx.
// ---------------------------------------------------------------------------
__global__ void decode_pack(const float* __restrict__ anchors,
                            const float* __restrict__ deltas,
                            const float* __restrict__ scores,
                            float* __restrict__ boxes,
                            u64* __restrict__ keys,
                            int N) {
#pragma clang fp contract(off)
    int n = blockIdx.x * blockDim.x + threadIdx.x;
    int b = blockIdx.y;
    if (n >= SORTN) return;
    u64* kb = keys + (size_t)b * SORTN;
    if (n < N) {
        float a0 = anchors[n * 4 + 0];
        float a1 = anchors[n * 4 + 1];
        float a2 = anchors[n * 4 + 2];
        float a3 = anchors[n * 4 + 3];
        float w = (a2 - a0) + 1.0f;
        float h = (a3 - a1) + 1.0f;
        float cx = a0 + 0.5f * w;
        float cy = a1 + 0.5f * h;
        const float* d = deltas + ((size_t)b * N + n) * 4;
        float dx = d[0], dy = d[1], dw = d[2], dh = d[3];
        float px = cx + w * dx;
        float py = cy + h * dy;
        float pw = (float)::exp((double)dw) * w;
        float ph = (float)::exp((double)dh) * h;
        float* bb = boxes + ((size_t)b * N + n) * 4;
        bb[0] = px - 0.5f * pw;
        bb[1] = py - 0.5f * ph;
        bb[2] = px + 0.5f * (pw - 2.0f);
        bb[3] = py + 0.5f * (ph - 2.0f);
        unsigned int sb = __float_as_uint(scores[(size_t)b * N + n]);
        kb[n] = ((u64)(~sb) << 32) | (u64)(unsigned int)n;
    } else {
        kb[n] = ~0ULL;
    }
}

// ---------------------------------------------------------------------------
// Hybrid bitonic sort (unchanged).
// ---------------------------------------------------------------------------
__global__ __launch_bounds__(1024) void bitonic_local_sort(u64* __restrict__ keys) {
    __shared__ u64 sk[TILE];
    int tile = blockIdx.x;
    u64* kb = keys + (size_t)tile * TILE;
    int base = (tile % NTILE) * TILE;
    for (int i = threadIdx.x; i < TILE; i += 1024) sk[i] = kb[i];
    __syncthreads();
    for (int k = 2; k <= TILE; k <<= 1) {
        for (int j = k >> 1; j > 0; j >>= 1) {
            for (int t = threadIdx.x; t < TILE / 2; t += 1024) {
                int i = ((t & ~(j - 1)) << 1) | (t & (j - 1));
                int ixj = i | j;
                u64 a = sk[i];
                u64 c = sk[ixj];
                bool up = (((base + i) & k) == 0);
                if ((a > c) == up) { sk[i] = c; sk[ixj] = a; }
            }
            __syncthreads();
        }
    }
    for (int i = threadIdx.x; i < TILE; i += 1024) kb[i] = sk[i];
}

__global__ void bitonic_global_step(u64* __restrict__ keys, int k, int j) {
    int t = blockIdx.x * blockDim.x + threadIdx.x;
    int b = t / (SORTN / 2);
    int s = t % (SORTN / 2);
    int i = ((s & ~(j - 1)) << 1) | (s & (j - 1));
    int ixj = i | j;
    u64* kb = keys + (size_t)b * SORTN;
    u64 a = kb[i];
    u64 c = kb[ixj];
    bool up = ((i & k) == 0);
    if ((a > c) == up) { kb[i] = c; kb[ixj] = a; }
}

__global__ __launch_bounds__(1024) void bitonic_local_merge(u64* __restrict__ keys, int k) {
    __shared__ u64 sk[TILE];
    int tile = blockIdx.x;
    u64* kb = keys + (size_t)tile * TILE;
    int base = (tile % NTILE) * TILE;
    bool up = ((base & k) == 0);
    for (int i = threadIdx.x; i < TILE; i += 1024) sk[i] = kb[i];
    __syncthreads();
    for (int j = TILE / 2; j > 0; j >>= 1) {
        for (int t = threadIdx.x; t < TILE / 2; t += 1024) {
            int i = ((t & ~(j - 1)) << 1) | (t & (j - 1));
            int ixj = i | j;
            u64 a = sk[i];
            u64 c = sk[ixj];
            if ((a > c) == up) { sk[i] = c; sk[ixj] = a; }
        }
        __syncthreads();
    }
    for (int i = threadIdx.x; i < TILE; i += 1024) kb[i] = sk[i];
}

// ---------------------------------------------------------------------------
// Gather sorted top-PADN boxes. Pad rows get far-away degenerate boxes.
// ---------------------------------------------------------------------------
__global__ void gather_sorted(const float* __restrict__ boxes,
                              const u64* __restrict__ keys,
                              float4* __restrict__ sbox, int N) {
    int r = blockIdx.x * 256 + threadIdx.x;
    int b = blockIdx.y;
    if (r >= PADN) return;
    float4 v;
    if (r < PRE_TOPN) {
        u64 key = keys[(size_t)b * SORTN + r];
        int n = (int)(unsigned)(key & 0xffffffffULL);
        v = ((const float4*)boxes)[(size_t)b * N + n];
    } else {
        v = make_float4(-4e8f, -4e8f, -4e8f, -4e8f);
    }
    sbox[(size_t)b * PADN + r] = v;
}

// ---------------------------------------------------------------------------
// Build suppression bitmap, torchvision-style: one THREAD per row, 64 column
// boxes staged in LDS, fully-unrolled inner loop builds the 64-bit word in a
// register. No per-thread arrays (round-3 version spilled them to scratch:
// VGPR_Count=16 + 1.5 GB FETCH). Grid: (cb, row-chunk, batch); triangular
// early-exit. Diagonal masked with wrap-safe (2ULL<<d)-1.
// bit j set iff col > row AND RN(inter/union) > 0.7f (margin filter; exact
// div only in ~1e-5 borderline band -> bit-identical decisions).
// ---------------------------------------------------------------------------
__global__ __launch_bounds__(256) void build_bitmap(const float4* __restrict__ sbox,
                                                    u64* __restrict__ bitmap) {
#pragma clang fp contract(off)
    int cb = blockIdx.x;        // column block 0..NBLK-1
    int chunk = blockIdx.y;     // row chunk (256 rows) 0..46
    int b = blockIdx.z;
    if (chunk * 4 > cb) return; // chunk's first row >= (cb+1)*64 -> empty
    int tid = threadIdx.x;

    __shared__ float4 cbox[64];
    __shared__ float carea[64];
    const float4* sb = sbox + (size_t)b * PADN;
    if (tid < 64) {
        float4 c4 = sb[cb * 64 + tid];
        cbox[tid] = c4;
        carea[tid] = ((c4.z - c4.x) + 1.0f) * ((c4.w - c4.y) + 1.0f);
    }
    int r = chunk * 256 + tid;            // r <= 46*256+255 = 12031 < PADN, always safe
    float4 me = sb[r];
    float ar = ((me.z - me.x) + 1.0f) * ((me.w - me.y) + 1.0f);
    __syncthreads();

    u64 word = 0;
#pragma unroll
    for (int j = 0; j < 64; ++j) {
        float4 cj = cbox[j];
        float aj = carea[j];
        float xx1 = fmaxf(me.x, cj.x);
        float yy1 = fmaxf(me.y, cj.y);
        float xx2 = fminf(me.z, cj.z);
        float yy2 = fminf(me.w, cj.w);
        float w = fmaxf((xx2 - xx1) + 1.0f, 0.0f);
        float h = fmaxf((yy2 - yy1) + 1.0f, 0.0f);
        float inter = w * h;
        float un = (ar + aj) - inter;
        float p = 0.7f * un;
        bool sup;
        if (inter > p * (1.0f + 1e-5f)) sup = true;
        else if (inter < p * (1.0f - 1e-5f)) sup = false;
        else sup = (inter / un) > 0.7f;   // rare borderline band: exact
        word |= ((u64)sup) << j;
    }
    // keep only cols strictly after this row (upper triangle)
    int d = r - cb * 64;
    if (d >= 0) word &= ~((2ULL << d) - 1ULL);   // d in [0,63]; d=63 wraps -> clear all

    if (r < (cb + 1) * 64) {
        bitmap[(size_t)b * TRI_WORDS + (size_t)32 * cb * (cb + 1) + (size_t)r] = word;
    }
}

// ---------------------------------------------------------------------------
// Sequential scan (unchanged from round 3).
// ---------------------------------------------------------------------------
__global__ __launch_bounds__(256) void scan_nms(const float4* __restrict__ sbox,
                                                const u64* __restrict__ bitmap,
                                                float* __restrict__ out) {
    int b = blockIdx.x;
    int tid = threadIdx.x;
    __shared__ u64 suppressed[NBLK];
    __shared__ u64 s_picks;
    __shared__ int s_K;
    if (tid < NBLK) suppressed[tid] = (tid == NBLK - 1) ? 0xFFFFFFFF00000000ULL : 0ULL;
    if (tid == 0) s_K = 0;
    const u64* bm = bitmap + (size_t)b * TRI_WORDS;

    for (int rb = 0; rb < NBLK; ++rb) {
        __syncthreads();
        int K = s_K;
        if (K >= POST_TOPN) break;
        if (tid < 64) {
            int c = tid;
            int base = rb * 64;
            u64 myrow = bm[(size_t)32 * rb * (rb + 1) + (size_t)(base + c)];
            float4 mybox = sbox[(size_t)b * PADN + base + c];
            u64 alive = ~suppressed[rb];
            u64 picks = 0;
            u64 cur = alive;
            while (cur) {
                int i = __ffsll((long long)cur) - 1;
                picks |= 1ULL << i;
                u64 row = shfl_u64(myrow, i);
                alive &= ~row;
                cur = alive & ~((2ULL << i) - 1ULL);
            }
            int avail = POST_TOPN - K;
            int np = __popcll(picks);
            while (np > avail) {
                picks &= ~(1ULL << (63 - __clzll(picks)));
                --np;
            }
            if (c == 0) { s_picks = picks; s_K = K + np; }
            if ((picks >> c) & 1ULL) {
                int rank = __popcll(picks & ((1ULL << c) - 1ULL));
                float* o = out + ((size_t)b * POST_TOPN + K + rank) * 5;
                o[0] = (float)b; o[1] = mybox.x; o[2] = mybox.y; o[3] = mybox.z; o[4] = mybox.w;
            }
        }
        __syncthreads();
        u64 pk = s_picks;
        if (pk) {
            int w = rb + 1 + tid;
            if (w < NBLK) {
                u64 acc = suppressed[w];
                const u64* col = bm + (size_t)32 * w * (w + 1) + (size_t)(rb * 64);
                u64 p2 = pk;
                while (p2) {
                    int i = __ffsll((long long)p2) - 1;
                    acc |= col[i];
                    p2 &= p2 - 1;
                }
                suppressed[w] = acc;
            }
        }
    }
    __syncthreads();
    int K = s_K;
    for (int r = K + tid; r < POST_TOPN; r += 256) {
        float* o = out + ((size_t)b * POST_TOPN + r) * 5;
        o[0] = 0.0f; o[1] = 0.0f; o[2] = 0.0f; o[3] = 0.0f; o[4] = 0.0f;
    }
}

// ---------------------------------------------------------------------------
// Fallback (round-2) NMS kernel — used only if ws_size can't hold the bitmap.
// ---------------------------------------------------------------------------
__global__ __launch_bounds__(1024) void nms_kernel(const float* __restrict__ boxes,
                                                   const u64* __restrict__ keys,
                                                   float* __restrict__ out,
                                                   int N) {
#pragma clang fp contract(off)
    __shared__ float4 kbox[POST_TOPN];
    __shared__ float kar[POST_TOPN];
    __shared__ float4 cbox[64];
    __shared__ float car_s[64];
    __shared__ int supp[64];
    __shared__ int s_cnt;

    int b = blockIdx.x;
    int tid = threadIdx.x;
    const u64* kb = keys + (size_t)b * SORTN;
    const float* bb = boxes + (size_t)b * N * 4;

    if (tid == 0) s_cnt = 0;
    __syncthreads();

    for (int start = 0; start < PRE_TOPN; start += 64) {
        int K = s_cnt;
        if (K >= POST_TOPN) break;
        int csize = min(64, PRE_TOPN - start);

        if (tid < 64) {
            int c = tid;
            if (c < csize) {
                u64 key = kb[start + c];
                int n = (int)(unsigned int)(key & 0xFFFFFFFFULL);
                const float* p = bb + (size_t)n * 4;
                float x1 = p[0], y1 = p[1], x2 = p[2], y2 = p[3];
                cbox[c] = make_float4(x1, y1, x2, y2);
                car_s[c] = ((x2 - x1) + 1.0f) * ((y2 - y1) + 1.0f);
            }
            supp[c] = 0;
        }
        __syncthreads();

        {
            int c = tid & 63;
            int sl = tid >> 6;
            if (c < csize) {
                float4 me = cbox[c];
                float ar = car_s[c];
                int flag = 0;
                for (int kk = sl; kk < K; kk += 16) {
                    float4 k0 = kbox[kk];
                    float a0 = kar[kk];
                    float xx1 = fmaxf(k0.x, me.x);
                    float yy1 = fmaxf(k0.y, me.y);
                    float xx2 = fminf(k0.z, me.z);
                    float yy2 = fminf(k0.w, me.w);
                    float w0 = fmaxf((xx2 - xx1) + 1.0f, 0.0f);
                    float h0 = fmaxf((yy2 - yy1) + 1.0f, 0.0f);
                    float inter0 = w0 * h0;
                    float iou0 = inter0 / ((a0 + ar) - inter0);
                    if (iou0 > 0.7f) { flag = 1; break; }
                }
                if (flag) supp[c] = 1;
            }
        }
        __syncthreads();

        if (tid < 64) {
            int c = tid;
            bool alive = (c < csize) && (supp[c] == 0);
            float4 me = cbox[c];
            float ar = car_s[c];
            int cnt = K;
            u64 m = __ballot(alive);
            while (m != 0 && cnt < POST_TOPN) {
                int i = __ffsll((unsigned long long)m) - 1;
                float ix1 = __shfl(me.x, i);
                float iy1 = __shfl(me.y, i);
                float ix2 = __shfl(me.z, i);
                float iy2 = __shfl(me.w, i);
                float iar = __shfl(ar, i);
                if (c == i) {
                    kbox[cnt] = me;
                    kar[cnt] = ar;
                    float* o = out + ((size_t)b * POST_TOPN + cnt) * 5;
                    o[0] = (float)b; o[1] = me.x; o[2] = me.y; o[3] = me.z; o[4] = me.w;
                }
                if (alive && c > i) {
                    float xx1 = fmaxf(ix1, me.x);
                    float yy1 = fmaxf(iy1, me.y);
                    float xx2 = fminf(ix2, me.z);
                    float yy2 = fminf(iy2, me.w);
                    float w = fmaxf((xx2 - xx1) + 1.0f, 0.0f);
                    float h = fmaxf((yy2 - yy1) + 1.0f, 0.0f);
                    float inter = w * h;
                    float iou = inter / ((iar + ar) - inter);
                    if (iou > 0.7f) alive = false;
                }
                cnt++;
                m = __ballot(alive);
                u64 clearmask = (2ULL << i) - 1ULL;
                m &= ~clearmask;
            }
            if (c == 0) s_cnt = cnt;
        }
        __syncthreads();
    }

    __syncthreads();
    int K = s_cnt;
    for (int r = K + tid; r < POST_TOPN; r += (int)blockDim.x) {
        float* o = out + ((size_t)b * POST_TOPN + r) * 5;
        o[0] = 0.0f; o[1] = 0.0f; o[2] = 0.0f; o[3] = 0.0f; o[4] = 0.0f;
    }
}

// ---------------------------------------------------------------------------
extern "C" void kernel_launch(void* const* d_in, const int* in_sizes, int n_in,
                              void* d_out, int out_size, void* d_ws, size_t ws_size,
                              hipStream_t stream) {
    const float* anchors = (const float*)d_in[0];
    const float* deltas  = (const float*)d_in[1];
    const float* scores  = (const float*)d_in[2];
    float* out = (float*)d_out;

    int N = in_sizes[0] / 4;           // 27380
    int B = in_sizes[2] / N;           // 8

    size_t off = 0;
    auto take = [&](size_t bytes) { size_t o = off; off = (off + bytes + 255) & ~(size_t)255; return o; };
    size_t boxesOff  = take((size_t)B * N * 4 * sizeof(float));
    size_t keysOff   = take((size_t)B * SORTN * sizeof(u64));
    size_t sboxOff   = take((size_t)B * PADN * sizeof(float4));
    size_t bitmapOff = take((size_t)B * TRI_WORDS * sizeof(u64));
    bool bitmap_path = (off <= ws_size);

    float* boxes = (float*)((char*)d_ws + boxesOff);
    u64*   keys  = (u64*)((char*)d_ws + keysOff);

    dim3 g1((unsigned)((SORTN + 255) / 256), (unsigned)B);
    decode_pack<<<g1, 256, 0, stream>>>(anchors, deltas, scores, boxes, keys, N);

    int ntiles = B * NTILE;
    bitonic_local_sort<<<ntiles, 1024, 0, stream>>>(keys);
    int gsteps = B * (SORTN / 2) / 256;
    bitonic_global_step<<<gsteps, 256, 0, stream>>>(keys, 2 * TILE, TILE);
    bitonic_local_merge<<<ntiles, 1024, 0, stream>>>(keys, 2 * TILE);
    bitonic_global_step<<<gsteps, 256, 0, stream>>>(keys, 4 * TILE, 2 * TILE);
    bitonic_global_step<<<gsteps, 256, 0, stream>>>(keys, 4 * TILE, TILE);
    bitonic_local_merge<<<ntiles, 1024, 0, stream>>>(keys, 4 * TILE);

    if (bitmap_path) {
        float4* sbox = (float4*)((char*)d_ws + sboxOff);
        u64* bitmap  = (u64*)((char*)d_ws + bitmapOff);
        dim3 gg((unsigned)((PADN + 255) / 256), (unsigned)B);
        gather_sorted<<<gg, 256, 0, stream>>>(boxes, keys, sbox, N);
        dim3 gb((unsigned)NBLK, 47u, (unsigned)B);
        build_bitmap<<<gb, 256, 0, stream>>>(sbox, bitmap);
        scan_nms<<<B, 256, 0, stream>>>(sbox, bitmap, out);
    } else {
        nms_kernel<<<B, 1024, 0, stream>>>(boxes, keys, out, N);
    }
}

// Round 5
// 883.150 us; speedup vs baseline: 1.8521x; 1.1634x over previous
//
#include <hip/hip_runtime.h>
#include <cmath>

typedef unsigned long long u64;

#define PRE_TOPN 12000
#define POST_TOPN 2000
#define SORTN 32768
#define TILE 8192
#define NTILE (SORTN / TILE)   // 4 tiles per batch
#define NBLK 188               // 64-bit column blocks covering 12032
#define PADN (NBLK * 64)       // 12032
// triangular bitmap: column-block cb stores rows 0..(cb+1)*64-1
// triOff(cb) = 32*cb*(cb+1); total words per batch:
#define TRI_WORDS (32 * (NBLK - 1) * NBLK + NBLK * 64)  // 1,137,024

__device__ inline u64 shfl_u64(u64 v, int lane) {
    int lo = __shfl((int)(unsigned)(v & 0xffffffffULL), lane);
    int hi = __shfl((int)(unsigned)(v >> 32), lane);
    return ((u64)(unsigned)hi << 32) | (u64)(unsigned)lo;
}

// ---------------------------------------------------------------------------
// Kernel 1: decode boxes (exact fp32 op order, no FMA contraction, exp via
// double) and pack sort keys. key = (~score_bits)<<32 | idx.
// ---------------------------------------------------------------------------
__global__ void decode_pack(const float* __restrict__ anchors,
                            const float* __restrict__ deltas,
                            const float* __restrict__ scores,
                            float* __restrict__ boxes,
                            u64* __restrict__ keys,
                            int N) {
#pragma clang fp contract(off)
    int n = blockIdx.x * blockDim.x + threadIdx.x;
    int b = blockIdx.y;
    if (n >= SORTN) return;
    u64* kb = keys + (size_t)b * SORTN;
    if (n < N) {
        float a0 = anchors[n * 4 + 0];
        float a1 = anchors[n * 4 + 1];
        float a2 = anchors[n * 4 + 2];
        float a3 = anchors[n * 4 + 3];
        float w = (a2 - a0) + 1.0f;
        float h = (a3 - a1) + 1.0f;
        float cx = a0 + 0.5f * w;
        float cy = a1 + 0.5f * h;
        const float* d = deltas + ((size_t)b * N + n) * 4;
        float dx = d[0], dy = d[1], dw = d[2], dh = d[3];
        float px = cx + w * dx;
        float py = cy + h * dy;
        float pw = (float)::exp((double)dw) * w;
        float ph = (float)::exp((double)dh) * h;
        float* bb = boxes + ((size_t)b * N + n) * 4;
        bb[0] = px - 0.5f * pw;
        bb[1] = py - 0.5f * ph;
        bb[2] = px + 0.5f * (pw - 2.0f);
        bb[3] = py + 0.5f * (ph - 2.0f);
        unsigned int sb = __float_as_uint(scores[(size_t)b * N + n]);
        kb[n] = ((u64)(~sb) << 32) | (u64)(unsigned int)n;
    } else {
        kb[n] = ~0ULL;
    }
}

// ---------------------------------------------------------------------------
// Hybrid bitonic sort (unchanged).
// ---------------------------------------------------------------------------
__global__ __launch_bounds__(1024) void bitonic_local_sort(u64* __restrict__ keys) {
    __shared__ u64 sk[TILE];
    int tile = blockIdx.x;
    u64* kb = keys + (size_t)tile * TILE;
    int base = (tile % NTILE) * TILE;
    for (int i = threadIdx.x; i < TILE; i += 1024) sk[i] = kb[i];
    __syncthreads();
    for (int k = 2; k <= TILE; k <<= 1) {
        for (int j = k >> 1; j > 0; j >>= 1) {
            for (int t = threadIdx.x; t < TILE / 2; t += 1024) {
                int i = ((t & ~(j - 1)) << 1) | (t & (j - 1));
                int ixj = i | j;
                u64 a = sk[i];
                u64 c = sk[ixj];
                bool up = (((base + i) & k) == 0);
                if ((a > c) == up) { sk[i] = c; sk[ixj] = a; }
            }
            __syncthreads();
        }
    }
    for (int i = threadIdx.x; i < TILE; i += 1024) kb[i] = sk[i];
}

__global__ void bitonic_global_step(u64* __restrict__ keys, int k, int j) {
    int t = blockIdx.x * blockDim.x + threadIdx.x;
    int b = t / (SORTN / 2);
    int s = t % (SORTN / 2);
    int i = ((s & ~(j - 1)) << 1) | (s & (j - 1));
    int ixj = i | j;
    u64* kb = keys + (size_t)b * SORTN;
    u64 a = kb[i];
    u64 c = kb[ixj];
    bool up = ((i & k) == 0);
    if ((a > c) == up) { kb[i] = c; kb[ixj] = a; }
}

__global__ __launch_bounds__(1024) void bitonic_local_merge(u64* __restrict__ keys, int k) {
    __shared__ u64 sk[TILE];
    int tile = blockIdx.x;
    u64* kb = keys + (size_t)tile * TILE;
    int base = (tile % NTILE) * TILE;
    bool up = ((base & k) == 0);
    for (int i = threadIdx.x; i < TILE; i += 1024) sk[i] = kb[i];
    __syncthreads();
    for (int j = TILE / 2; j > 0; j >>= 1) {
        for (int t = threadIdx.x; t < TILE / 2; t += 1024) {
            int i = ((t & ~(j - 1)) << 1) | (t & (j - 1));
            int ixj = i | j;
            u64 a = sk[i];
            u64 c = sk[ixj];
            if ((a > c) == up) { sk[i] = c; sk[ixj] = a; }
        }
        __syncthreads();
    }
    for (int i = threadIdx.x; i < TILE; i += 1024) kb[i] = sk[i];
}

// ---------------------------------------------------------------------------
// Gather sorted top-PADN boxes. Pad rows get far-away degenerate boxes.
// ---------------------------------------------------------------------------
__global__ void gather_sorted(const float* __restrict__ boxes,
                              const u64* __restrict__ keys,
                              float4* __restrict__ sbox, int N) {
    int r = blockIdx.x * 256 + threadIdx.x;
    int b = blockIdx.y;
    if (r >= PADN) return;
    float4 v;
    if (r < PRE_TOPN) {
        u64 key = keys[(size_t)b * SORTN + r];
        int n = (int)(unsigned)(key & 0xffffffffULL);
        v = ((const float4*)boxes)[(size_t)b * N + n];
    } else {
        v = make_float4(-4e8f, -4e8f, -4e8f, -4e8f);
    }
    sbox[(size_t)b * PADN + r] = v;
}

// ---------------------------------------------------------------------------
// Build suppression bitmap: one THREAD per row, 64 column boxes in LDS,
// fully-unrolled inner loop builds the 64-bit word in a register.
//
// Predicate (division-free, bit-exact vs reference):
//   un = (ai+aj) - inter > 0 holds for all boxes here (areas positive,
//   inter <= min area). For un>0:
//     RN_f32(inter/un) > 0.7f  <=>  inter/un >= m,  m = 0.7f + 2^-25
//   (0.7f mantissa is odd -> the half-ulp tie rounds UP to the even
//   neighbor, so the midpoint itself satisfies '>'). m has 25 sig bits,
//   un has 24 -> m*un is EXACT in double (<=49 bits), so
//     (double)inter >= m_d*(double)un
//   reproduces the reference decision bit-for-bit with no division.
//   (Round-4's margin filter got if-converted: the full correctly-rounded
//   f32 div ladder ran for EVERY pair -> ~2.3x instruction bloat.)
// ---------------------------------------------------------------------------
__global__ __launch_bounds__(256) void build_bitmap(const float4* __restrict__ sbox,
                                                    u64* __restrict__ bitmap) {
#pragma clang fp contract(off)
    const double MD = (double)0.7f + 0x1p-25;   // exact midpoint multiplier
    int cb = blockIdx.x;        // column block 0..NBLK-1
    int chunk = blockIdx.y;     // row chunk (256 rows) 0..46
    int b = blockIdx.z;
    if (chunk * 4 > cb) return; // chunk's first row >= (cb+1)*64 -> empty
    int tid = threadIdx.x;

    __shared__ float4 cbox[64];
    __shared__ float carea[64];
    const float4* sb = sbox + (size_t)b * PADN;
    if (tid < 64) {
        float4 c4 = sb[cb * 64 + tid];
        cbox[tid] = c4;
        carea[tid] = ((c4.z - c4.x) + 1.0f) * ((c4.w - c4.y) + 1.0f);
    }
    int r = chunk * 256 + tid;            // r <= 12031 < PADN, always safe
    float4 me = sb[r];
    float ar = ((me.z - me.x) + 1.0f) * ((me.w - me.y) + 1.0f);
    __syncthreads();

    u64 word = 0;
#pragma unroll
    for (int j = 0; j < 64; ++j) {
        float4 cj = cbox[j];
        float aj = carea[j];
        float xx1 = fmaxf(me.x, cj.x);
        float yy1 = fmaxf(me.y, cj.y);
        float xx2 = fminf(me.z, cj.z);
        float yy2 = fminf(me.w, cj.w);
        float w = fmaxf((xx2 - xx1) + 1.0f, 0.0f);
        float h = fmaxf((yy2 - yy1) + 1.0f, 0.0f);
        float inter = w * h;
        float un = (ar + aj) - inter;
        bool sup = ((double)inter >= MD * (double)un);
        word |= ((u64)sup) << j;
    }
    // keep only cols strictly after this row (upper triangle)
    int d = r - cb * 64;
    if (d >= 0) word &= ~((2ULL << d) - 1ULL);   // d in [0,63]; d=63 wraps -> clear all

    if (r < (cb + 1) * 64) {
        bitmap[(size_t)b * TRI_WORDS + (size_t)32 * cb * (cb + 1) + (size_t)r] = word;
    }
}

// ---------------------------------------------------------------------------
// Sequential scan (unchanged).
// ---------------------------------------------------------------------------
__global__ __launch_bounds__(256) void scan_nms(const float4* __restrict__ sbox,
                                                const u64* __restrict__ bitmap,
                                                float* __restrict__ out) {
    int b = blockIdx.x;
    int tid = threadIdx.x;
    __shared__ u64 suppressed[NBLK];
    __shared__ u64 s_picks;
    __shared__ int s_K;
    if (tid < NBLK) suppressed[tid] = (tid == NBLK - 1) ? 0xFFFFFFFF00000000ULL : 0ULL;
    if (tid == 0) s_K = 0;
    const u64* bm = bitmap + (size_t)b * TRI_WORDS;

    for (int rb = 0; rb < NBLK; ++rb) {
        __syncthreads();
        int K = s_K;
        if (K >= POST_TOPN) break;
        if (tid < 64) {
            int c = tid;
            int base = rb * 64;
            u64 myrow = bm[(size_t)32 * rb * (rb + 1) + (size_t)(base + c)];
            float4 mybox = sbox[(size_t)b * PADN + base + c];
            u64 alive = ~suppressed[rb];
            u64 picks = 0;
            u64 cur = alive;
            while (cur) {
                int i = __ffsll((long long)cur) - 1;
                picks |= 1ULL << i;
                u64 row = shfl_u64(myrow, i);
                alive &= ~row;
                cur = alive & ~((2ULL << i) - 1ULL);
            }
            int avail = POST_TOPN - K;
            int np = __popcll(picks);
            while (np > avail) {
                picks &= ~(1ULL << (63 - __clzll(picks)));
                --np;
            }
            if (c == 0) { s_picks = picks; s_K = K + np; }
            if ((picks >> c) & 1ULL) {
                int rank = __popcll(picks & ((1ULL << c) - 1ULL));
                float* o = out + ((size_t)b * POST_TOPN + K + rank) * 5;
                o[0] = (float)b; o[1] = mybox.x; o[2] = mybox.y; o[3] = mybox.z; o[4] = mybox.w;
            }
        }
        __syncthreads();
        u64 pk = s_picks;
        if (pk) {
            int w = rb + 1 + tid;
            if (w < NBLK) {
                u64 acc = suppressed[w];
                const u64* col = bm + (size_t)32 * w * (w + 1) + (size_t)(rb * 64);
                u64 p2 = pk;
                while (p2) {
                    int i = __ffsll((long long)p2) - 1;
                    acc |= col[i];
                    p2 &= p2 - 1;
                }
                suppressed[w] = acc;
            }
        }
    }
    __syncthreads();
    int K = s_K;
    for (int r = K + tid; r < POST_TOPN; r += 256) {
        float* o = out + ((size_t)b * POST_TOPN + r) * 5;
        o[0] = 0.0f; o[1] = 0.0f; o[2] = 0.0f; o[3] = 0.0f; o[4] = 0.0f;
    }
}

// ---------------------------------------------------------------------------
// Fallback (round-2) NMS kernel — used only if ws_size can't hold the bitmap.
// ---------------------------------------------------------------------------
__global__ __launch_bounds__(1024) void nms_kernel(const float* __restrict__ boxes,
                                                   const u64* __restrict__ keys,
                                                   float* __restrict__ out,
                                                   int N) {
#pragma clang fp contract(off)
    __shared__ float4 kbox[POST_TOPN];
    __shared__ float kar[POST_TOPN];
    __shared__ float4 cbox[64];
    __shared__ float car_s[64];
    __shared__ int supp[64];
    __shared__ int s_cnt;

    int b = blockIdx.x;
    int tid = threadIdx.x;
    const u64* kb = keys + (size_t)b * SORTN;
    const float* bb = boxes + (size_t)b * N * 4;

    if (tid == 0) s_cnt = 0;
    __syncthreads();

    for (int start = 0; start < PRE_TOPN; start += 64) {
        int K = s_cnt;
        if (K >= POST_TOPN) break;
        int csize = min(64, PRE_TOPN - start);

        if (tid < 64) {
            int c = tid;
            if (c < csize) {
                u64 key = kb[start + c];
                int n = (int)(unsigned int)(key & 0xFFFFFFFFULL);
                const float* p = bb + (size_t)n * 4;
                float x1 = p[0], y1 = p[1], x2 = p[2], y2 = p[3];
                cbox[c] = make_float4(x1, y1, x2, y2);
                car_s[c] = ((x2 - x1) + 1.0f) * ((y2 - y1) + 1.0f);
            }
            supp[c] = 0;
        }
        __syncthreads();

        {
            int c = tid & 63;
            int sl = tid >> 6;
            if (c < csize) {
                float4 me = cbox[c];
                float ar = car_s[c];
                int flag = 0;
                for (int kk = sl; kk < K; kk += 16) {
                    float4 k0 = kbox[kk];
                    float a0 = kar[kk];
                    float xx1 = fmaxf(k0.x, me.x);
                    float yy1 = fmaxf(k0.y, me.y);
                    float xx2 = fminf(k0.z, me.z);
                    float yy2 = fminf(k0.w, me.w);
                    float w0 = fmaxf((xx2 - xx1) + 1.0f, 0.0f);
                    float h0 = fmaxf((yy2 - yy1) + 1.0f, 0.0f);
                    float inter0 = w0 * h0;
                    float iou0 = inter0 / ((a0 + ar) - inter0);
                    if (iou0 > 0.7f) { flag = 1; break; }
                }
                if (flag) supp[c] = 1;
            }
        }
        __syncthreads();

        if (tid < 64) {
            int c = tid;
            bool alive = (c < csize) && (supp[c] == 0);
            float4 me = cbox[c];
            float ar = car_s[c];
            int cnt = K;
            u64 m = __ballot(alive);
            while (m != 0 && cnt < POST_TOPN) {
                int i = __ffsll((unsigned long long)m) - 1;
                float ix1 = __shfl(me.x, i);
                float iy1 = __shfl(me.y, i);
                float ix2 = __shfl(me.z, i);
                float iy2 = __shfl(me.w, i);
                float iar = __shfl(ar, i);
                if (c == i) {
                    kbox[cnt] = me;
                    kar[cnt] = ar;
                    float* o = out + ((size_t)b * POST_TOPN + cnt) * 5;
                    o[0] = (float)b; o[1] = me.x; o[2] = me.y; o[3] = me.z; o[4] = me.w;
                }
                if (alive && c > i) {
                    float xx1 = fmaxf(ix1, me.x);
                    float yy1 = fmaxf(iy1, me.y);
                    float xx2 = fminf(ix2, me.z);
                    float yy2 = fminf(iy2, me.w);
                    float w = fmaxf((xx2 - xx1) + 1.0f, 0.0f);
                    float h = fmaxf((yy2 - yy1) + 1.0f, 0.0f);
                    float inter = w * h;
                    float iou = inter / ((iar + ar) - inter);
                    if (iou > 0.7f) alive = false;
                }
                cnt++;
                m = __ballot(alive);
                u64 clearmask = (2ULL << i) - 1ULL;
                m &= ~clearmask;
            }
            if (c == 0) s_cnt = cnt;
        }
        __syncthreads();
    }

    __syncthreads();
    int K = s_cnt;
    for (int r = K + tid; r < POST_TOPN; r += (int)blockDim.x) {
        float* o = out + ((size_t)b * POST_TOPN + r) * 5;
        o[0] = 0.0f; o[1] = 0.0f; o[2] = 0.0f; o[3] = 0.0f; o[4] = 0.0f;
    }
}

// ---------------------------------------------------------------------------
extern "C" void kernel_launch(void* const* d_in, const int* in_sizes, int n_in,
                              void* d_out, int out_size, void* d_ws, size_t ws_size,
                              hipStream_t stream) {
    const float* anchors = (const float*)d_in[0];
    const float* deltas  = (const float*)d_in[1];
    const float* scores  = (const float*)d_in[2];
    float* out = (float*)d_out;

    int N = in_sizes[0] / 4;           // 27380
    int B = in_sizes[2] / N;           // 8

    size_t off = 0;
    auto take = [&](size_t bytes) { size_t o = off; off = (off + bytes + 255) & ~(size_t)255; return o; };
    size_t boxesOff  = take((size_t)B * N * 4 * sizeof(float));
    size_t keysOff   = take((size_t)B * SORTN * sizeof(u64));
    size_t sboxOff   = take((size_t)B * PADN * sizeof(float4));
    size_t bitmapOff = take((size_t)B * TRI_WORDS * sizeof(u64));
    bool bitmap_path = (off <= ws_size);

    float* boxes = (float*)((char*)d_ws + boxesOff);
    u64*   keys  = (u64*)((char*)d_ws + keysOff);

    dim3 g1((unsigned)((SORTN + 255) / 256), (unsigned)B);
    decode_pack<<<g1, 256, 0, stream>>>(anchors, deltas, scores, boxes, keys, N);

    int ntiles = B * NTILE;
    bitonic_local_sort<<<ntiles, 1024, 0, stream>>>(keys);
    int gsteps = B * (SORTN / 2) / 256;
    bitonic_global_step<<<gsteps, 256, 0, stream>>>(keys, 2 * TILE, TILE);
    bitonic_local_merge<<<ntiles, 1024, 0, stream>>>(keys, 2 * TILE);
    bitonic_global_step<<<gsteps, 256, 0, stream>>>(keys, 4 * TILE, 2 * TILE);
    bitonic_global_step<<<gsteps, 256, 0, stream>>>(keys, 4 * TILE, TILE);
    bitonic_local_merge<<<ntiles, 1024, 0, stream>>>(keys, 4 * TILE);

    if (bitmap_path) {
        float4* sbox = (float4*)((char*)d_ws + sboxOff);
        u64* bitmap  = (u64*)((char*)d_ws + bitmapOff);
        dim3 gg((unsigned)((PADN + 255) / 256), (unsigned)B);
        gather_sorted<<<gg, 256, 0, stream>>>(boxes, keys, sbox, N);
        dim3 gb((unsigned)NBLK, 47u, (unsigned)B);
        build_bitmap<<<gb, 256, 0, stream>>>(sbox, bitmap);
        scan_nms<<<B, 256, 0, stream>>>(sbox, bitmap, out);
    } else {
        nms_kernel<<<B, 1024, 0, stream>>>(boxes, keys, out, N);
    }
}

// Round 6
// 660.022 us; speedup vs baseline: 2.4783x; 1.3381x over previous
//
#include <hip/hip_runtime.h>
#include <cmath>

typedef unsigned long long u64;

#define PRE_TOPN 12000
#define POST_TOPN 2000
#define SORTN 32768
#define TILE 8192
#define NTILE (SORTN / TILE)   // 4 tiles per batch
#define NBLK 188               // 64-bit column blocks covering 12032
#define PADN (NBLK * 64)       // 12032
// triangular bitmap: column-block cb stores rows 0..(cb+1)*64-1
// triOff(cb) = 32*cb*(cb+1); total words per batch:
#define TRI_WORDS (32 * (NBLK - 1) * NBLK + NBLK * 64)  // 1,137,024

__device__ inline u64 shfl_u64(u64 v, int lane) {
    int lo = __shfl((int)(unsigned)(v & 0xffffffffULL), lane);
    int hi = __shfl((int)(unsigned)(v >> 32), lane);
    return ((u64)(unsigned)hi << 32) | (u64)(unsigned)lo;
}

__device__ inline u64 shfl_xor_u64(u64 v, int mask) {
    int lo = __shfl_xor((int)(unsigned)(v & 0xffffffffULL), mask);
    int hi = __shfl_xor((int)(unsigned)(v >> 32), mask);
    return ((u64)(unsigned)hi << 32) | (u64)(unsigned)lo;
}

// ---------------------------------------------------------------------------
// Kernel 1: decode boxes (exact fp32 op order, no FMA contraction, exp via
// double) and pack sort keys. key = (~score_bits)<<32 | idx.
// ---------------------------------------------------------------------------
__global__ void decode_pack(const float* __restrict__ anchors,
                            const float* __restrict__ deltas,
                            const float* __restrict__ scores,
                            float* __restrict__ boxes,
                            u64* __restrict__ keys,
                            int N) {
#pragma clang fp contract(off)
    int n = blockIdx.x * blockDim.x + threadIdx.x;
    int b = blockIdx.y;
    if (n >= SORTN) return;
    u64* kb = keys + (size_t)b * SORTN;
    if (n < N) {
        float a0 = anchors[n * 4 + 0];
        float a1 = anchors[n * 4 + 1];
        float a2 = anchors[n * 4 + 2];
        float a3 = anchors[n * 4 + 3];
        float w = (a2 - a0) + 1.0f;
        float h = (a3 - a1) + 1.0f;
        float cx = a0 + 0.5f * w;
        float cy = a1 + 0.5f * h;
        const float* d = deltas + ((size_t)b * N + n) * 4;
        float dx = d[0], dy = d[1], dw = d[2], dh = d[3];
        float px = cx + w * dx;
        float py = cy + h * dy;
        float pw = (float)::exp((double)dw) * w;
        float ph = (float)::exp((double)dh) * h;
        float* bb = boxes + ((size_t)b * N + n) * 4;
        bb[0] = px - 0.5f * pw;
        bb[1] = py - 0.5f * ph;
        bb[2] = px + 0.5f * (pw - 2.0f);
        bb[3] = py + 0.5f * (ph - 2.0f);
        unsigned int sb = __float_as_uint(scores[(size_t)b * N + n]);
        kb[n] = ((u64)(~sb) << 32) | (u64)(unsigned int)n;
    } else {
        kb[n] = ~0ULL;
    }
}

// ---------------------------------------------------------------------------
// Hybrid bitonic sort (unchanged).
// ---------------------------------------------------------------------------
__global__ __launch_bounds__(1024) void bitonic_local_sort(u64* __restrict__ keys) {
    __shared__ u64 sk[TILE];
    int tile = blockIdx.x;
    u64* kb = keys + (size_t)tile * TILE;
    int base = (tile % NTILE) * TILE;
    for (int i = threadIdx.x; i < TILE; i += 1024) sk[i] = kb[i];
    __syncthreads();
    for (int k = 2; k <= TILE; k <<= 1) {
        for (int j = k >> 1; j > 0; j >>= 1) {
            for (int t = threadIdx.x; t < TILE / 2; t += 1024) {
                int i = ((t & ~(j - 1)) << 1) | (t & (j - 1));
                int ixj = i | j;
                u64 a = sk[i];
                u64 c = sk[ixj];
                bool up = (((base + i) & k) == 0);
                if ((a > c) == up) { sk[i] = c; sk[ixj] = a; }
            }
            __syncthreads();
        }
    }
    for (int i = threadIdx.x; i < TILE; i += 1024) kb[i] = sk[i];
}

__global__ void bitonic_global_step(u64* __restrict__ keys, int k, int j) {
    int t = blockIdx.x * blockDim.x + threadIdx.x;
    int b = t / (SORTN / 2);
    int s = t % (SORTN / 2);
    int i = ((s & ~(j - 1)) << 1) | (s & (j - 1));
    int ixj = i | j;
    u64* kb = keys + (size_t)b * SORTN;
    u64 a = kb[i];
    u64 c = kb[ixj];
    bool up = ((i & k) == 0);
    if ((a > c) == up) { kb[i] = c; kb[ixj] = a; }
}

__global__ __launch_bounds__(1024) void bitonic_local_merge(u64* __restrict__ keys, int k) {
    __shared__ u64 sk[TILE];
    int tile = blockIdx.x;
    u64* kb = keys + (size_t)tile * TILE;
    int base = (tile % NTILE) * TILE;
    bool up = ((base & k) == 0);
    for (int i = threadIdx.x; i < TILE; i += 1024) sk[i] = kb[i];
    __syncthreads();
    for (int j = TILE / 2; j > 0; j >>= 1) {
        for (int t = threadIdx.x; t < TILE / 2; t += 1024) {
            int i = ((t & ~(j - 1)) << 1) | (t & (j - 1));
            int ixj = i | j;
            u64 a = sk[i];
            u64 c = sk[ixj];
            if ((a > c) == up) { sk[i] = c; sk[ixj] = a; }
        }
        __syncthreads();
    }
    for (int i = threadIdx.x; i < TILE; i += 1024) kb[i] = sk[i];
}

// ---------------------------------------------------------------------------
// Gather sorted top-PADN boxes. Pad rows get far-away degenerate boxes.
// ---------------------------------------------------------------------------
__global__ void gather_sorted(const float* __restrict__ boxes,
                              const u64* __restrict__ keys,
                              float4* __restrict__ sbox, int N) {
    int r = blockIdx.x * 256 + threadIdx.x;
    int b = blockIdx.y;
    if (r >= PADN) return;
    float4 v;
    if (r < PRE_TOPN) {
        u64 key = keys[(size_t)b * SORTN + r];
        int n = (int)(unsigned)(key & 0xffffffffULL);
        v = ((const float4*)boxes)[(size_t)b * N + n];
    } else {
        v = make_float4(-4e8f, -4e8f, -4e8f, -4e8f);
    }
    sbox[(size_t)b * PADN + r] = v;
}

// ---------------------------------------------------------------------------
// Build suppression bitmap: one THREAD per row, 64 column boxes in LDS,
// fully-unrolled inner loop builds the 64-bit word in a register.
// Predicate is division-free and bit-exact vs the reference (see round-5
// notes): RN_f32(inter/un) > 0.7f  <=>  (double)inter >= MD*(double)un,
// MD = 0.7f + 2^-25 (exact product: 25+24 bits <= 53).
// ---------------------------------------------------------------------------
__global__ __launch_bounds__(256) void build_bitmap(const float4* __restrict__ sbox,
                                                    u64* __restrict__ bitmap) {
#pragma clang fp contract(off)
    const double MD = (double)0.7f + 0x1p-25;   // exact midpoint multiplier
    int cb = blockIdx.x;        // column block 0..NBLK-1
    int chunk = blockIdx.y;     // row chunk (256 rows) 0..46
    int b = blockIdx.z;
    if (chunk * 4 > cb) return; // chunk's first row >= (cb+1)*64 -> empty
    int tid = threadIdx.x;

    __shared__ float4 cbox[64];
    __shared__ float carea[64];
    const float4* sb = sbox + (size_t)b * PADN;
    if (tid < 64) {
        float4 c4 = sb[cb * 64 + tid];
        cbox[tid] = c4;
        carea[tid] = ((c4.z - c4.x) + 1.0f) * ((c4.w - c4.y) + 1.0f);
    }
    int r = chunk * 256 + tid;            // r <= 12031 < PADN, always safe
    float4 me = sb[r];
    float ar = ((me.z - me.x) + 1.0f) * ((me.w - me.y) + 1.0f);
    __syncthreads();

    u64 word = 0;
#pragma unroll
    for (int j = 0; j < 64; ++j) {
        float4 cj = cbox[j];
        float aj = carea[j];
        float xx1 = fmaxf(me.x, cj.x);
        float yy1 = fmaxf(me.y, cj.y);
        float xx2 = fminf(me.z, cj.z);
        float yy2 = fminf(me.w, cj.w);
        float w = fmaxf((xx2 - xx1) + 1.0f, 0.0f);
        float h = fmaxf((yy2 - yy1) + 1.0f, 0.0f);
        float inter = w * h;
        float un = (ar + aj) - inter;
        bool sup = ((double)inter >= MD * (double)un);
        word |= ((u64)sup) << j;
    }
    // keep only cols strictly after this row (upper triangle)
    int d = r - cb * 64;
    if (d >= 0) word &= ~((2ULL << d) - 1ULL);   // d in [0,63]; d=63 wraps -> clear all

    if (r < (cb + 1) * 64) {
        bitmap[(size_t)b * TRI_WORDS + (size_t)32 * cb * (cb + 1) + (size_t)r] = word;
    }
}

// ---------------------------------------------------------------------------
// Sequential scan, DEFERRED-OR version. One block (256 thr) per batch.
// Pick list (global row indices, <=2000) lives in LDS. On entering block rb:
//   sup(rb) = OR over all prior picks p of slab_rb[p]
// gathered by all 256 threads with x4 manual unroll (independent loads, ~2
// vmcnt waits) instead of round-5's serialized per-pick global walks.
// Wave 0 prefetches its diagonal word + box before the gather, resolves the
// intra-block greedy picks via ballot-free bit ops + shfl, appends picks,
// writes ROIs in pick order. Semantics identical to round-5 scan.
// ---------------------------------------------------------------------------
__global__ __launch_bounds__(256) void scan_nms(const float4* __restrict__ sbox,
                                                const u64* __restrict__ bitmap,
                                                float* __restrict__ out) {
    int b = blockIdx.x;
    int tid = threadIdx.x;
    int lane = tid & 63;
    int wv = tid >> 6;
    __shared__ int picks_lds[POST_TOPN];   // 8 KB
    __shared__ u64 s_partial[4];
    __shared__ int s_K;

    if (tid == 0) s_K = 0;
    __syncthreads();

    const u64* bm = bitmap + (size_t)b * TRI_WORDS;

    for (int rb = 0; rb < NBLK; ++rb) {
        int K = s_K;                       // uniform (post-barrier)
        if (K >= POST_TOPN) break;
        const u64* slab = bm + (size_t)32 * rb * (rb + 1);  // rows 0..(rb+1)*64-1
        int base = rb * 64;

        // wave-0 prefetch (issues before the gather's waits)
        u64 myrow = 0;
        float4 mybox = make_float4(0.f, 0.f, 0.f, 0.f);
        if (wv == 0) {
            myrow = slab[base + lane];
            mybox = sbox[(size_t)b * PADN + base + lane];
        }

        // deferred gather: OR suppression words of all prior picks
        u64 sup = 0;
        {
            int t = tid;
            for (; t + 768 < K; t += 1024) {
                u64 w0 = slab[picks_lds[t]];
                u64 w1 = slab[picks_lds[t + 256]];
                u64 w2 = slab[picks_lds[t + 512]];
                u64 w3 = slab[picks_lds[t + 768]];
                sup |= (w0 | w1) | (w2 | w3);
            }
            for (; t < K; t += 256) sup |= slab[picks_lds[t]];
        }
        // 64-lane butterfly OR-reduce, then cross-wave partials
        for (int off = 1; off < 64; off <<= 1) sup |= shfl_xor_u64(sup, off);
        if (lane == 0) s_partial[wv] = sup;
        __syncthreads();

        if (wv == 0) {
            u64 total = s_partial[0] | s_partial[1] | s_partial[2] | s_partial[3];
            if (rb == NBLK - 1) total |= 0xFFFFFFFF00000000ULL;   // pad rows >= 12000
            int c = lane;
            u64 alive = ~total;
            u64 picks = 0;
            u64 cur = alive;
            while (cur) {
                int i = __ffsll((long long)cur) - 1;
                picks |= 1ULL << i;
                u64 row = shfl_u64(myrow, i);
                alive &= ~row;
                cur = alive & ~((2ULL << i) - 1ULL);
            }
            int avail = POST_TOPN - K;
            int np = __popcll(picks);
            while (np > avail) {                       // truncate latest picks
                picks &= ~(1ULL << (63 - __clzll(picks)));
                --np;
            }
            if ((picks >> c) & 1ULL) {
                int rank = __popcll(picks & ((1ULL << c) - 1ULL));
                picks_lds[K + rank] = base + c;
                float* o = out + ((size_t)b * POST_TOPN + K + rank) * 5;
                o[0] = (float)b; o[1] = mybox.x; o[2] = mybox.y; o[3] = mybox.z; o[4] = mybox.w;
            }
            if (c == 0) s_K = K + np;
        }
        __syncthreads();
    }

    int K = s_K;
    for (int r = K + tid; r < POST_TOPN; r += 256) {
        float* o = out + ((size_t)b * POST_TOPN + r) * 5;
        o[0] = 0.0f; o[1] = 0.0f; o[2] = 0.0f; o[3] = 0.0f; o[4] = 0.0f;
    }
}

// ---------------------------------------------------------------------------
// Fallback (round-2) NMS kernel — used only if ws_size can't hold the bitmap.
// ---------------------------------------------------------------------------
__global__ __launch_bounds__(1024) void nms_kernel(const float* __restrict__ boxes,
                                                   const u64* __restrict__ keys,
                                                   float* __restrict__ out,
                                                   int N) {
#pragma clang fp contract(off)
    __shared__ float4 kbox[POST_TOPN];
    __shared__ float kar[POST_TOPN];
    __shared__ float4 cbox[64];
    __shared__ float car_s[64];
    __shared__ int supp[64];
    __shared__ int s_cnt;

    int b = blockIdx.x;
    int tid = threadIdx.x;
    const u64* kb = keys + (size_t)b * SORTN;
    const float* bb = boxes + (size_t)b * N * 4;

    if (tid == 0) s_cnt = 0;
    __syncthreads();

    for (int start = 0; start < PRE_TOPN; start += 64) {
        int K = s_cnt;
        if (K >= POST_TOPN) break;
        int csize = min(64, PRE_TOPN - start);

        if (tid < 64) {
            int c = tid;
            if (c < csize) {
                u64 key = kb[start + c];
                int n = (int)(unsigned int)(key & 0xFFFFFFFFULL);
                const float* p = bb + (size_t)n * 4;
                float x1 = p[0], y1 = p[1], x2 = p[2], y2 = p[3];
                cbox[c] = make_float4(x1, y1, x2, y2);
                car_s[c] = ((x2 - x1) + 1.0f) * ((y2 - y1) + 1.0f);
            }
            supp[c] = 0;
        }
        __syncthreads();

        {
            int c = tid & 63;
            int sl = tid >> 6;
            if (c < csize) {
                float4 me = cbox[c];
                float ar = car_s[c];
                int flag = 0;
                for (int kk = sl; kk < K; kk += 16) {
                    float4 k0 = kbox[kk];
                    float a0 = kar[kk];
                    float xx1 = fmaxf(k0.x, me.x);
                    float yy1 = fmaxf(k0.y, me.y);
                    float xx2 = fminf(k0.z, me.z);
                    float yy2 = fminf(k0.w, me.w);
                    float w0 = fmaxf((xx2 - xx1) + 1.0f, 0.0f);
                    float h0 = fmaxf((yy2 - yy1) + 1.0f, 0.0f);
                    float inter0 = w0 * h0;
                    float iou0 = inter0 / ((a0 + ar) - inter0);
                    if (iou0 > 0.7f) { flag = 1; break; }
                }
                if (flag) supp[c] = 1;
            }
        }
        __syncthreads();

        if (tid < 64) {
            int c = tid;
            bool alive = (c < csize) && (supp[c] == 0);
            float4 me = cbox[c];
            float ar = car_s[c];
            int cnt = K;
            u64 m = __ballot(alive);
            while (m != 0 && cnt < POST_TOPN) {
                int i = __ffsll((unsigned long long)m) - 1;
                float ix1 = __shfl(me.x, i);
                float iy1 = __shfl(me.y, i);
                float ix2 = __shfl(me.z, i);
                float iy2 = __shfl(me.w, i);
                float iar = __shfl(ar, i);
                if (c == i) {
                    kbox[cnt] = me;
                    kar[cnt] = ar;
                    float* o = out + ((size_t)b * POST_TOPN + cnt) * 5;
                    o[0] = (float)b; o[1] = me.x; o[2] = me.y; o[3] = me.z; o[4] = me.w;
                }
                if (alive && c > i) {
                    float xx1 = fmaxf(ix1, me.x);
                    float yy1 = fmaxf(iy1, me.y);
                    float xx2 = fminf(ix2, me.z);
                    float yy2 = fminf(iy2, me.w);
                    float w = fmaxf((xx2 - xx1) + 1.0f, 0.0f);
                    float h = fmaxf((yy2 - yy1) + 1.0f, 0.0f);
                    float inter = w * h;
                    float iou = inter / ((iar + ar) - inter);
                    if (iou > 0.7f) alive = false;
                }
                cnt++;
                m = __ballot(alive);
                u64 clearmask = (2ULL << i) - 1ULL;
                m &= ~clearmask;
            }
            if (c == 0) s_cnt = cnt;
        }
        __syncthreads();
    }

    __syncthreads();
    int K = s_cnt;
    for (int r = K + tid; r < POST_TOPN; r += (int)blockDim.x) {
        float* o = out + ((size_t)b * POST_TOPN + r) * 5;
        o[0] = 0.0f; o[1] = 0.0f; o[2] = 0.0f; o[3] = 0.0f; o[4] = 0.0f;
    }
}

// ---------------------------------------------------------------------------
extern "C" void kernel_launch(void* const* d_in, const int* in_sizes, int n_in,
                              void* d_out, int out_size, void* d_ws, size_t ws_size,
                              hipStream_t stream) {
    const float* anchors = (const float*)d_in[0];
    const float* deltas  = (const float*)d_in[1];
    const float* scores  = (const float*)d_in[2];
    float* out = (float*)d_out;

    int N = in_sizes[0] / 4;           // 27380
    int B = in_sizes[2] / N;           // 8

    size_t off = 0;
    auto take = [&](size_t bytes) { size_t o = off; off = (off + bytes + 255) & ~(size_t)255; return o; };
    size_t boxesOff  = take((size_t)B * N * 4 * sizeof(float));
    size_t keysOff   = take((size_t)B * SORTN * sizeof(u64));
    size_t sboxOff   = take((size_t)B * PADN * sizeof(float4));
    size_t bitmapOff = take((size_t)B * TRI_WORDS * sizeof(u64));
    bool bitmap_path = (off <= ws_size);

    float* boxes = (float*)((char*)d_ws + boxesOff);
    u64*   keys  = (u64*)((char*)d_ws + keysOff);

    dim3 g1((unsigned)((SORTN + 255) / 256), (unsigned)B);
    decode_pack<<<g1, 256, 0, stream>>>(anchors, deltas, scores, boxes, keys, N);

    int ntiles = B * NTILE;
    bitonic_local_sort<<<ntiles, 1024, 0, stream>>>(keys);
    int gsteps = B * (SORTN / 2) / 256;
    bitonic_global_step<<<gsteps, 256, 0, stream>>>(keys, 2 * TILE, TILE);
    bitonic_local_merge<<<ntiles, 1024, 0, stream>>>(keys, 2 * TILE);
    bitonic_global_step<<<gsteps, 256, 0, stream>>>(keys, 4 * TILE, 2 * TILE);
    bitonic_global_step<<<gsteps, 256, 0, stream>>>(keys, 4 * TILE, TILE);
    bitonic_local_merge<<<ntiles, 1024, 0, stream>>>(keys, 4 * TILE);

    if (bitmap_path) {
        float4* sbox = (float4*)((char*)d_ws + sboxOff);
        u64* bitmap  = (u64*)((char*)d_ws + bitmapOff);
        dim3 gg((unsigned)((PADN + 255) / 256), (unsigned)B);
        gather_sorted<<<gg, 256, 0, stream>>>(boxes, keys, sbox, N);
        dim3 gb((unsigned)NBLK, 47u, (unsigned)B);
        build_bitmap<<<gb, 256, 0, stream>>>(sbox, bitmap);
        scan_nms<<<B, 256, 0, stream>>>(sbox, bitmap, out);
    } else {
        nms_kernel<<<B, 1024, 0, stream>>>(boxes, keys, out, N);
    }
}